// Round 15
// baseline (58.739 us; speedup 1.0000x reference)
//
#include <hip/hip_runtime.h>
#include <math.h>

#define NB     24
#define FBIN   512
#define ROWS   (32*1200)
#define GRID   2048
#define BLK    256
#define WPB    4
#define NWAVES (GRID*WPB)    // 8192 waves; 4-5 rows each
#define SLOTS  20            // stride 80 B -> 16B-aligned b128 reads
#define LOG2E  1.44269504f

typedef float f32x4 __attribute__((ext_vector_type(4)));

__device__ __constant__ int   c_off[NB+1] = {0,3,6,9,12,16,20,24,29,34,40,47,55,64,74,86,100,118,140,169,204,246,304,384,512};
__device__ __constant__ float c_k[NB]     = {3,3,3,3,4,4,4,5,5,6,7,8,9,10,12,14,18,22,29,35,42,58,80,128};

#define RDLANE(v,i) __int_as_float(__builtin_amdgcn_readlane(__float_as_int(v), (i)))
#define NTLD(p)     __builtin_nontemporal_load((const f32x4*)(p))

__global__ __launch_bounds__(BLK) void pe_main(const float* __restrict__ lm,
                                               const float* __restrict__ re,
                                               const float* __restrict__ im,
                                               const float* __restrict__ S,
                                               float* __restrict__ partial)
{
    __shared__ float s_slot[WPB][2][NB*SLOTS];   // parity dbuf, 15.4 KB
    __shared__ float s_red[WPB];

    const int tid  = threadIdx.x;
    const int w    = tid >> 6;
    const int lane = tid & 63;

    // zero this wave's two slot buffers (pads stay 0 forever)
    {
        float* sw = &s_slot[w][0][0];
        for (int i = lane; i < 2*NB*SLOTS; i += 64) sw[i] = 0.f;
    }

    // ---- per-lane row-invariant metadata (8 contiguous bins per lane) ----
    const int bin0 = lane * 8;
    int waddr[8], band4[8];
    unsigned smask = 0;
    float rtq[8], a4[8];
    #pragma unroll
    for (int j = 0; j < 8; ++j) {
        const int binj = bin0 + j;
        int b = 0;
        for (int q = 0; q < NB; ++q) if (binj >= c_off[q+1]) b++;
        band4[j] = b << 2;
        waddr[j] = b*SLOTS + (lane - (c_off[b] >> 3));
        if (j > 0 && waddr[j] == waddr[j-1]) smask |= 1u << j;
        const float z = (binj + 1) * 0.03125f;
        const float tqj = 3.64f*__builtin_amdgcn_exp2f(-0.8f*__builtin_amdgcn_logf(z + 1e-6f))
                        - 6.5f*__builtin_amdgcn_exp2f(-0.6f*LOG2E*(z-3.3f)*(z-3.3f))
                        + 1e-3f*z*z*z*z;
        a4[j] = 1.5f / c_k[b];            // 2/denom == rsqrt(a4 * t); weight = a4/57600
        rtq[j] = (tqj > 0.f) ? __builtin_amdgcn_rsqf(a4[j] * tqj) : 3.4e38f;
    }

    // S column for my band (lanes 0-23) + 1/(colsum+eps), in registers
    const int cl = (lane < NB) ? lane : NB-1;
    float Sreg[NB];
    float colsum = 1e-8f;
    #pragma unroll
    for (int i = 0; i < NB; ++i) { Sreg[i] = S[i*NB + cl]; colsum += Sreg[i]; }
    const float invcol  = 1.0f / colsum;
    const float abandcl = 1.5f / c_k[cl];

    const int gw = blockIdx.x * WPB + w;
    size_t base = (size_t)gw * FBIN + bin0;
    const size_t step = (size_t)NWAVES * FBIN;

    // preload row 0 of ALL THREE streams (non-temporal: working set thrashes L2 anyway)
    f32x4 L0 = NTLD(lm + base), L1 = NTLD(lm + base + 4);
    f32x4 R0 = NTLD(re + base), R1 = NTLD(re + base + 4);
    f32x4 I0 = NTLD(im + base), I1 = NTLD(im + base + 4);

    float acc = 0.f;
    int par = 0;
    for (int row = gw; row < ROWS; row += NWAVES) {
        const float lmv[8] = {L0.x,L0.y,L0.z,L0.w,L1.x,L1.y,L1.z,L1.w};
        float sp[8];
        #pragma unroll
        for (int j = 0; j < 8; ++j)
            sp[j] = __builtin_amdgcn_exp2f(fminf(lmv[j], 10.f) * LOG2E);

        float* const slot = &s_slot[w][par][0];
        // branchless segmented stores: cumulative rewrite, last write per slot wins
        {
            float ps = sp[0];
            slot[waddr[0]] = ps;
            #pragma unroll
            for (int j = 1; j < 8; ++j) {
                ps = ((smask >> j) & 1u) ? ps + sp[j] : sp[j];
                slot[waddr[j]] = ps;
            }
        }

        // FULL next-row prefetch (all 3 streams), issued before the LDS drain
        const size_t nb = base + ((row + NWAVES < ROWS) ? step : (size_t)0);
        const f32x4 nL0 = NTLD(lm + nb), nL1 = NTLD(lm + nb + 4);
        const f32x4 nR0 = NTLD(re + nb), nR1 = NTLD(re + nb + 4);
        const f32x4 nI0 = NTLD(im + nb), nI1 = NTLD(im + nb + 4);

        asm volatile("s_waitcnt lgkmcnt(0)" ::: "memory");   // own-wave store visibility

        // per-band sums (lanes 0-23): 5x b128 from zero-padded slots
        float psum_v = 0.f;
        if (lane < NB) {
            const float4* q = (const float4*)(slot + lane*SLOTS);
            const float4 q0=q[0], q1=q[1], q2=q[2], q3=q[3], q4=q[4];
            psum_v = ((((q0.x+q0.y)+(q0.z+q0.w)) + ((q1.x+q1.y)+(q1.z+q1.w)))
                   +  (((q2.x+q2.y)+(q2.z+q2.w)) + ((q3.x+q3.y)+(q3.z+q3.w))))
                   +   ((q4.x+q4.y)+(q4.z+q4.w));
        }

        // t = (psum@S + eps)*invcol; psum broadcast via readlane, S from registers;
        // one rsq per band: vb = rsqrt(a4_band * t)
        float vb;
        {
            float c0 = 1e-8f, c1 = 0.f, c2 = 0.f, c3 = 0.f;
            #pragma unroll
            for (int i = 0; i < NB; i += 4) {
                c0 = fmaf(RDLANE(psum_v,i+0), Sreg[i+0], c0);
                c1 = fmaf(RDLANE(psum_v,i+1), Sreg[i+1], c1);
                c2 = fmaf(RDLANE(psum_v,i+2), Sreg[i+2], c2);
                c3 = fmaf(RDLANE(psum_v,i+3), Sreg[i+3], c3);
            }
            const float tmine = ((c0+c1)+(c2+c3)) * invcol;
            vb = __builtin_amdgcn_rsqf(abandcl * tmine);
        }

        // broadcast vb[band] to all lanes via bpermute
        float vbb[8];
        #pragma unroll
        for (int j = 0; j < 8; ++j)
            vbb[j] = __int_as_float(__builtin_amdgcn_ds_bpermute(band4[j], __float_as_int(vb)));

        const float rv[8] = {R0.x,R0.y,R0.z,R0.w,R1.x,R1.y,R1.z,R1.w};
        const float iv[8] = {I0.x,I0.y,I0.z,I0.w,I1.x,I1.y,I1.z,I1.w};
        #pragma unroll
        for (int j = 0; j < 8; ++j) {
            const float u  = sp[j] * fminf(vbb[j], rtq[j]);   // == sp*rsqrt(a4*max(t,tq))
            const float pr = fmaf(fabsf(rv[j]), u, 1.0f);
            const float pi = fmaf(fabsf(iv[j]), u, 1.0f);
            acc = fmaf(__builtin_amdgcn_logf(pr * pi), a4[j], acc);
        }

        par ^= 1;                 // parity dbuf: no tail drain needed
        L0 = nL0; L1 = nL1; R0 = nR0; R1 = nR1; I0 = nI0; I1 = nI1;
        base += step;
    }

    // wave reduce -> cross-wave block reduce (one partial per BLOCK)
    #pragma unroll
    for (int o = 32; o > 0; o >>= 1) acc += __shfl_xor(acc, o, 64);
    if (lane == 0) s_red[w] = acc;
    __syncthreads();
    if (tid == 0)
        partial[blockIdx.x] = (s_red[0] + s_red[1] + s_red[2] + s_red[3]) * (1.0f/57600.0f);
}

__global__ __launch_bounds__(256) void pe_final(const float* __restrict__ partial,
                                                float* __restrict__ out)
{
    __shared__ double sred[256];
    const int tid = threadIdx.x;
    double s = 0.0;
    #pragma unroll
    for (int i = tid; i < GRID; i += 256) s += (double)partial[i];
    sred[tid] = s;
    __syncthreads();
    for (int k = 128; k > 0; k >>= 1) {
        if (tid < k) sred[tid] += sred[tid+k];
        __syncthreads();
    }
    if (tid == 0) out[0] = (float)(1.0 / (sred[0] + 1.0));
}

extern "C" void kernel_launch(void* const* d_in, const int* in_sizes, int n_in,
                              void* d_out, int out_size, void* d_ws, size_t ws_size,
                              hipStream_t stream) {
    const float* lm = (const float*)d_in[0];
    const float* re = (const float*)d_in[1];
    const float* im = (const float*)d_in[2];
    const float* S  = (const float*)d_in[3];
    float* partial = (float*)d_ws;   // GRID floats = 8 KB scratch
    pe_main<<<GRID, BLK, 0, stream>>>(lm, re, im, S, partial);
    pe_final<<<1, 256, 0, stream>>>(partial, (float*)d_out);
}

// Round 18
// 45.887 us; speedup vs baseline: 1.2801x; 1.2801x over previous
//
#include <hip/hip_runtime.h>
#include <math.h>

#define NB     24
#define FBIN   512
#define ROWS   (32*1200)
#define GRID   2048
#define BLK    256
#define WPB    4
#define NWAVES (GRID*WPB)    // 8192 waves; 4-5 rows each
#define SLOTS  20            // stride 80 B -> 16B-aligned b128 reads
#define LOG2E  1.44269504f

__device__ __constant__ int   c_off[NB+1] = {0,3,6,9,12,16,20,24,29,34,40,47,55,64,74,86,100,118,140,169,204,246,304,384,512};
__device__ __constant__ float c_k[NB]     = {3,3,3,3,4,4,4,5,5,6,7,8,9,10,12,14,18,22,29,35,42,58,80,128};

#define RDLANE(v,i) __int_as_float(__builtin_amdgcn_readlane(__float_as_int(v), (i)))

__global__ __launch_bounds__(BLK) void pe_main(const float* __restrict__ lm,
                                               const float* __restrict__ re,
                                               const float* __restrict__ im,
                                               const float* __restrict__ S,
                                               float* __restrict__ partial)
{
    __shared__ float s_slot[WPB][2][NB*SLOTS];   // parity dbuf, 15.4 KB
    __shared__ float s_red[WPB];

    const int tid  = threadIdx.x;
    const int w    = tid >> 6;
    const int lane = tid & 63;

    // zero this wave's two slot buffers (pads stay 0 forever)
    {
        float* sw = &s_slot[w][0][0];
        for (int i = lane; i < 2*NB*SLOTS; i += 64) sw[i] = 0.f;
    }

    // ---- per-lane row-invariant metadata (8 contiguous bins per lane) ----
    const int bin0 = lane * 8;
    int waddr[8], band4[8];
    unsigned smask = 0;
    float rtq[8], a4[8];
    #pragma unroll
    for (int j = 0; j < 8; ++j) {
        const int binj = bin0 + j;
        int b = 0;
        for (int q = 0; q < NB; ++q) if (binj >= c_off[q+1]) b++;
        band4[j] = b << 2;
        waddr[j] = b*SLOTS + (lane - (c_off[b] >> 3));
        if (j > 0 && waddr[j] == waddr[j-1]) smask |= 1u << j;
        const float z = (binj + 1) * 0.03125f;
        const float tqj = 3.64f*__builtin_amdgcn_exp2f(-0.8f*__builtin_amdgcn_logf(z + 1e-6f))
                        - 6.5f*__builtin_amdgcn_exp2f(-0.6f*LOG2E*(z-3.3f)*(z-3.3f))
                        + 1e-3f*z*z*z*z;
        a4[j] = 1.5f / c_k[b];            // 2/denom == rsqrt(a4 * t); weight = a4/57600
        // rsqrt(a4*max(t,tq)) == min(rsqrt(a4*t), rtq); tq<=0 never binds
        rtq[j] = (tqj > 0.f) ? __builtin_amdgcn_rsqf(a4[j] * tqj) : 3.4e38f;
    }

    // S column for my band (lanes 0-23) + 1/(colsum+eps), in registers
    const int cl = (lane < NB) ? lane : NB-1;
    float Sreg[NB];
    float colsum = 1e-8f;
    #pragma unroll
    for (int i = 0; i < NB; ++i) { Sreg[i] = S[i*NB + cl]; colsum += Sreg[i]; }
    const float invcol  = 1.0f / colsum;
    const float abandcl = 1.5f / c_k[cl];

    const int gw = blockIdx.x * WPB + w;
    size_t base = (size_t)gw * FBIN + bin0;
    const size_t step = (size_t)NWAVES * FBIN;

    // preload row 0 of ALL THREE streams
    float4 L0 = *(const float4*)(lm + base), L1 = *(const float4*)(lm + base + 4);
    float4 R0 = *(const float4*)(re + base), R1 = *(const float4*)(re + base + 4);
    float4 I0 = *(const float4*)(im + base), I1 = *(const float4*)(im + base + 4);

    float acc = 0.f;
    int par = 0;
    for (int row = gw; row < ROWS; row += NWAVES) {
        const float lmv[8] = {L0.x,L0.y,L0.z,L0.w,L1.x,L1.y,L1.z,L1.w};
        float sp[8];
        #pragma unroll
        for (int j = 0; j < 8; ++j)
            sp[j] = __builtin_amdgcn_exp2f(fminf(lmv[j], 10.f) * LOG2E);

        float* const slot = &s_slot[w][par][0];
        // branchless segmented stores: cumulative rewrite, last write per slot wins
        {
            float ps = sp[0];
            slot[waddr[0]] = ps;
            #pragma unroll
            for (int j = 1; j < 8; ++j) {
                ps = ((smask >> j) & 1u) ? ps + sp[j] : sp[j];
                slot[waddr[j]] = ps;
            }
        }

        // FULL next-row prefetch (all 3 streams), issued before the LDS drain
        const size_t nb = base + ((row + NWAVES < ROWS) ? step : (size_t)0);
        const float4 nL0 = *(const float4*)(lm + nb), nL1 = *(const float4*)(lm + nb + 4);
        const float4 nR0 = *(const float4*)(re + nb), nR1 = *(const float4*)(re + nb + 4);
        const float4 nI0 = *(const float4*)(im + nb), nI1 = *(const float4*)(im + nb + 4);

        asm volatile("s_waitcnt lgkmcnt(0)" ::: "memory");   // own-wave store visibility

        // per-band sums (lanes 0-23): 5x b128 from zero-padded slots
        float psum_v = 0.f;
        if (lane < NB) {
            const float4* q = (const float4*)(slot + lane*SLOTS);
            const float4 q0=q[0], q1=q[1], q2=q[2], q3=q[3], q4=q[4];
            psum_v = ((((q0.x+q0.y)+(q0.z+q0.w)) + ((q1.x+q1.y)+(q1.z+q1.w)))
                   +  (((q2.x+q2.y)+(q2.z+q2.w)) + ((q3.x+q3.y)+(q3.z+q3.w))))
                   +   ((q4.x+q4.y)+(q4.z+q4.w));
        }

        // t = (psum@S + eps)*invcol; psum broadcast via readlane, S from registers;
        // one rsq per band: vb = rsqrt(a4_band * t)
        float vb;
        {
            float c0 = 1e-8f, c1 = 0.f, c2 = 0.f, c3 = 0.f;
            #pragma unroll
            for (int i = 0; i < NB; i += 4) {
                c0 = fmaf(RDLANE(psum_v,i+0), Sreg[i+0], c0);
                c1 = fmaf(RDLANE(psum_v,i+1), Sreg[i+1], c1);
                c2 = fmaf(RDLANE(psum_v,i+2), Sreg[i+2], c2);
                c3 = fmaf(RDLANE(psum_v,i+3), Sreg[i+3], c3);
            }
            const float tmine = ((c0+c1)+(c2+c3)) * invcol;
            vb = __builtin_amdgcn_rsqf(abandcl * tmine);
        }

        // broadcast vb[band] to all lanes via bpermute
        float vbb[8];
        #pragma unroll
        for (int j = 0; j < 8; ++j)
            vbb[j] = __int_as_float(__builtin_amdgcn_ds_bpermute(band4[j], __float_as_int(vb)));

        const float rv[8] = {R0.x,R0.y,R0.z,R0.w,R1.x,R1.y,R1.z,R1.w};
        const float iv[8] = {I0.x,I0.y,I0.z,I0.w,I1.x,I1.y,I1.z,I1.w};
        #pragma unroll
        for (int j = 0; j < 8; ++j) {
            const float u  = sp[j] * fminf(vbb[j], rtq[j]);   // == sp*rsqrt(a4*max(t,tq))
            const float pr = fmaf(fabsf(rv[j]), u, 1.0f);
            const float pi = fmaf(fabsf(iv[j]), u, 1.0f);
            acc = fmaf(__builtin_amdgcn_logf(pr * pi), a4[j], acc);
        }

        par ^= 1;                 // parity dbuf: no tail drain needed
        L0 = nL0; L1 = nL1; R0 = nR0; R1 = nR1; I0 = nI0; I1 = nI1;
        base += step;
    }

    // wave reduce -> cross-wave block reduce (one partial per BLOCK)
    #pragma unroll
    for (int o = 32; o > 0; o >>= 1) acc += __shfl_xor(acc, o, 64);
    if (lane == 0) s_red[w] = acc;
    __syncthreads();
    if (tid == 0)
        partial[blockIdx.x] = (s_red[0] + s_red[1] + s_red[2] + s_red[3]) * (1.0f/57600.0f);
}

__global__ __launch_bounds__(256) void pe_final(const float* __restrict__ partial,
                                                float* __restrict__ out)
{
    __shared__ double sred[256];
    const int tid = threadIdx.x;
    double s = 0.0;
    for (int i = tid; i < GRID; i += 256) s += (double)partial[i];
    sred[tid] = s;
    __syncthreads();
    for (int k = 128; k > 0; k >>= 1) {
        if (tid < k) sred[tid] += sred[tid+k];
        __syncthreads();
    }
    if (tid == 0) out[0] = (float)(1.0 / (sred[0] + 1.0));
}

extern "C" void kernel_launch(void* const* d_in, const int* in_sizes, int n_in,
                              void* d_out, int out_size, void* d_ws, size_t ws_size,
                              hipStream_t stream) {
    const float* lm = (const float*)d_in[0];
    const float* re = (const float*)d_in[1];
    const float* im = (const float*)d_in[2];
    const float* S  = (const float*)d_in[3];
    float* partial = (float*)d_ws;   // GRID floats = 8 KB scratch
    pe_main<<<GRID, BLK, 0, stream>>>(lm, re, im, S, partial);
    pe_final<<<1, 256, 0, stream>>>(partial, (float*)d_out);
}

// Round 20
// 45.531 us; speedup vs baseline: 1.2901x; 1.0078x over previous
//
#include <hip/hip_runtime.h>
#include <math.h>

#define NB     24
#define FBIN   512
#define ROWS   (32*1200)
#define GRID   2048
#define BLK    256
#define WPB    4
#define NWAVES (GRID*WPB)    // 8192 waves; 4-5 rows each
#define SLOTS  20            // stride 80 B -> 16B-aligned b128 reads
#define LOG2E  1.44269504f

__device__ __constant__ int   c_off[NB+1] = {0,3,6,9,12,16,20,24,29,34,40,47,55,64,74,86,100,118,140,169,204,246,304,384,512};
__device__ __constant__ float c_k[NB]     = {3,3,3,3,4,4,4,5,5,6,7,8,9,10,12,14,18,22,29,35,42,58,80,128};

#define RDLANE(v,i) __int_as_float(__builtin_amdgcn_readlane(__float_as_int(v), (i)))

__global__ __launch_bounds__(BLK) void pe_main(const float* __restrict__ lm,
                                               const float* __restrict__ re,
                                               const float* __restrict__ im,
                                               const float* __restrict__ S,
                                               float* __restrict__ partial)
{
    __shared__ float s_slot[WPB][2][NB*SLOTS];   // parity dbuf, 15.4 KB
    __shared__ float s_red[WPB];

    const int tid  = threadIdx.x;
    const int w    = tid >> 6;
    const int lane = tid & 63;

    // zero this wave's two slot buffers (pads stay 0 forever)
    {
        float* sw = &s_slot[w][0][0];
        for (int i = lane; i < 2*NB*SLOTS; i += 64) sw[i] = 0.f;
    }

    // ---- per-lane row-invariant metadata (8 contiguous bins per lane) ----
    const int bin0 = lane * 8;
    int waddr[8], band4[8];
    unsigned smask = 0;
    float rtq[8], a4[8];
    #pragma unroll
    for (int j = 0; j < 8; ++j) {
        const int binj = bin0 + j;
        int b = 0;
        for (int q = 0; q < NB; ++q) if (binj >= c_off[q+1]) b++;
        band4[j] = b << 2;
        waddr[j] = b*SLOTS + (lane - (c_off[b] >> 3));
        if (j > 0 && waddr[j] == waddr[j-1]) smask |= 1u << j;
        const float z = (binj + 1) * 0.03125f;
        const float tqj = 3.64f*__builtin_amdgcn_exp2f(-0.8f*__builtin_amdgcn_logf(z + 1e-6f))
                        - 6.5f*__builtin_amdgcn_exp2f(-0.6f*LOG2E*(z-3.3f)*(z-3.3f))
                        + 1e-3f*z*z*z*z;
        a4[j] = 1.5f / c_k[b];            // 2/denom == rsqrt(a4 * t); weight = a4/57600
        // rsqrt(a4*max(t,tq)) == min(rsqrt(a4*t), rtq); tq<=0 never binds
        rtq[j] = (tqj > 0.f) ? __builtin_amdgcn_rsqf(a4[j] * tqj) : 3.4e38f;
    }

    // S column for my band (lanes 0-23) + 1/(colsum+eps), in registers
    const int cl = (lane < NB) ? lane : NB-1;
    float Sreg[NB];
    float colsum = 1e-8f;
    #pragma unroll
    for (int i = 0; i < NB; ++i) { Sreg[i] = S[i*NB + cl]; colsum += Sreg[i]; }
    const float invcol  = 1.0f / colsum;
    const float abandcl = 1.5f / c_k[cl];

    const int gw = blockIdx.x * WPB + w;
    size_t base = (size_t)gw * FBIN + bin0;
    const size_t step = (size_t)NWAVES * FBIN;

    // preload row 0 of ALL THREE streams
    float4 L0 = *(const float4*)(lm + base), L1 = *(const float4*)(lm + base + 4);
    float4 R0 = *(const float4*)(re + base), R1 = *(const float4*)(re + base + 4);
    float4 I0 = *(const float4*)(im + base), I1 = *(const float4*)(im + base + 4);

    float acc = 0.f;
    int par = 0;
    for (int row = gw; row < ROWS; row += NWAVES) {
        const float lmv[8] = {L0.x,L0.y,L0.z,L0.w,L1.x,L1.y,L1.z,L1.w};
        float sp[8];
        #pragma unroll
        for (int j = 0; j < 8; ++j)
            sp[j] = __builtin_amdgcn_exp2f(fminf(lmv[j], 10.f) * LOG2E);

        float* const slot = &s_slot[w][par][0];
        // branchless segmented stores: cumulative rewrite, last write per slot wins
        {
            float ps = sp[0];
            slot[waddr[0]] = ps;
            #pragma unroll
            for (int j = 1; j < 8; ++j) {
                ps = ((smask >> j) & 1u) ? ps + sp[j] : sp[j];
                slot[waddr[j]] = ps;
            }
        }

        // FULL next-row prefetch (all 3 streams), issued before the LDS drain
        const size_t nb = base + ((row + NWAVES < ROWS) ? step : (size_t)0);
        const float4 nL0 = *(const float4*)(lm + nb), nL1 = *(const float4*)(lm + nb + 4);
        const float4 nR0 = *(const float4*)(re + nb), nR1 = *(const float4*)(re + nb + 4);
        const float4 nI0 = *(const float4*)(im + nb), nI1 = *(const float4*)(im + nb + 4);

        asm volatile("s_waitcnt lgkmcnt(0)" ::: "memory");   // own-wave store visibility

        // per-band sums (lanes 0-23): 5x b128 from zero-padded slots
        float psum_v = 0.f;
        if (lane < NB) {
            const float4* q = (const float4*)(slot + lane*SLOTS);
            const float4 q0=q[0], q1=q[1], q2=q[2], q3=q[3], q4=q[4];
            psum_v = ((((q0.x+q0.y)+(q0.z+q0.w)) + ((q1.x+q1.y)+(q1.z+q1.w)))
                   +  (((q2.x+q2.y)+(q2.z+q2.w)) + ((q3.x+q3.y)+(q3.z+q3.w))))
                   +   ((q4.x+q4.y)+(q4.z+q4.w));
        }

        // t = (psum@S + eps)*invcol; psum broadcast via readlane, S from registers;
        // one rsq per band: vb = rsqrt(a4_band * t)
        float vb;
        {
            float c0 = 1e-8f, c1 = 0.f, c2 = 0.f, c3 = 0.f;
            #pragma unroll
            for (int i = 0; i < NB; i += 4) {
                c0 = fmaf(RDLANE(psum_v,i+0), Sreg[i+0], c0);
                c1 = fmaf(RDLANE(psum_v,i+1), Sreg[i+1], c1);
                c2 = fmaf(RDLANE(psum_v,i+2), Sreg[i+2], c2);
                c3 = fmaf(RDLANE(psum_v,i+3), Sreg[i+3], c3);
            }
            const float tmine = ((c0+c1)+(c2+c3)) * invcol;
            vb = __builtin_amdgcn_rsqf(abandcl * tmine);
        }

        // broadcast vb[band] to all lanes via bpermute
        float vbb[8];
        #pragma unroll
        for (int j = 0; j < 8; ++j)
            vbb[j] = __int_as_float(__builtin_amdgcn_ds_bpermute(band4[j], __float_as_int(vb)));

        const float rv[8] = {R0.x,R0.y,R0.z,R0.w,R1.x,R1.y,R1.z,R1.w};
        const float iv[8] = {I0.x,I0.y,I0.z,I0.w,I1.x,I1.y,I1.z,I1.w};
        #pragma unroll
        for (int j = 0; j < 8; ++j) {
            const float u  = sp[j] * fminf(vbb[j], rtq[j]);   // == sp*rsqrt(a4*max(t,tq))
            const float pr = fmaf(fabsf(rv[j]), u, 1.0f);
            const float pi = fmaf(fabsf(iv[j]), u, 1.0f);
            acc = fmaf(__builtin_amdgcn_logf(pr * pi), a4[j], acc);
        }

        par ^= 1;                 // parity dbuf: no tail drain needed
        L0 = nL0; L1 = nL1; R0 = nR0; R1 = nR1; I0 = nI0; I1 = nI1;
        base += step;
    }

    // wave reduce -> cross-wave block reduce (one partial per BLOCK)
    #pragma unroll
    for (int o = 32; o > 0; o >>= 1) acc += __shfl_xor(acc, o, 64);
    if (lane == 0) s_red[w] = acc;
    __syncthreads();
    if (tid == 0)
        partial[blockIdx.x] = (s_red[0] + s_red[1] + s_red[2] + s_red[3]) * (1.0f/57600.0f);
}

__global__ __launch_bounds__(256) void pe_final(const float* __restrict__ partial,
                                                float* __restrict__ out)
{
    __shared__ double sred[256];
    const int tid = threadIdx.x;
    double s = 0.0;
    for (int i = tid; i < GRID; i += 256) s += (double)partial[i];
    sred[tid] = s;
    __syncthreads();
    for (int k = 128; k > 0; k >>= 1) {
        if (tid < k) sred[tid] += sred[tid+k];
        __syncthreads();
    }
    if (tid == 0) out[0] = (float)(1.0 / (sred[0] + 1.0));
}

extern "C" void kernel_launch(void* const* d_in, const int* in_sizes, int n_in,
                              void* d_out, int out_size, void* d_ws, size_t ws_size,
                              hipStream_t stream) {
    const float* lm = (const float*)d_in[0];
    const float* re = (const float*)d_in[1];
    const float* im = (const float*)d_in[2];
    const float* S  = (const float*)d_in[3];
    float* partial = (float*)d_ws;   // GRID floats = 8 KB scratch
    pe_main<<<GRID, BLK, 0, stream>>>(lm, re, im, S, partial);
    pe_final<<<1, 256, 0, stream>>>(partial, (float*)d_out);
}